// Round 1
// baseline (1661.310 us; speedup 1.0000x reference)
//
#include <hip/hip_runtime.h>
#include <cstddef>

#define N_DIM 64
#define C_IN 64
#define C_OUT 128
#define T_DIM 300
#define V_DIM 25
#define KK 3
#define TCH 25     // t columns per block
#define XROW 32    // padded x_lds row width (t-dim), >= 28 for tg=7 reads

// ---------------- prep: build s, Weff [v][i][c], beff [v][c] ----------------
__global__ __launch_bounds__(256)
void sgc_prep(const float* __restrict__ A, const float* __restrict__ W,
              const float* __restrict__ bias, const int* __restrict__ index,
              float* __restrict__ Weff, float* __restrict__ beff) {
  const int v = blockIdx.x;
  const int idx = index[v];
  float s0 = 0.f, s1 = 0.f, s2 = 0.f;
  for (int w = 0; w < V_DIM; ++w) {
    s0 += A[(0 * V_DIM + idx) * V_DIM + w];
    s1 += A[(1 * V_DIM + idx) * V_DIM + w];
    s2 += A[(2 * V_DIM + idx) * V_DIM + w];
  }
  for (int e = threadIdx.x; e < C_IN * C_OUT; e += blockDim.x) {
    const int i = e >> 7;            // /128
    const int c = e & (C_OUT - 1);   // %128
    const float wv = s0 * W[(0 * C_OUT + c) * C_IN + i] +
                     s1 * W[(1 * C_OUT + c) * C_IN + i] +
                     s2 * W[(2 * C_OUT + c) * C_IN + i];
    Weff[(size_t)v * C_IN * C_OUT + e] = wv;   // [v][i][c]
  }
  if (threadIdx.x < C_OUT) {
    const int c = threadIdx.x;
    beff[v * C_OUT + c] = s0 * bias[0 * C_OUT + c] +
                          s1 * bias[1 * C_OUT + c] +
                          s2 * bias[2 * C_OUT + c];
  }
}

// ---------------- main: per-v GEMM, double-buffered LDS ----------------
__global__ __launch_bounds__(256, 2)
void sgc_main(const float* __restrict__ x, const float* __restrict__ Weff,
              const float* __restrict__ beff, float* __restrict__ out) {
  __shared__ float w_lds[2][C_IN * C_OUT];   // 2 x 32 KB, [i][c]
  __shared__ float x_lds[2][C_IN * XROW];    // 2 x  8 KB, [i][tl]

  const int n  = blockIdx.y;
  const int t0 = blockIdx.x * TCH;
  const int tid = threadIdx.x;
  const int cg = tid & 31;     // 32 c-groups
  const int tg = tid >> 5;     // 8 t-groups
  const int c4 = cg * 4;
  const int t4 = tg * 4;

  const float* __restrict__ xn = x + (size_t)n * C_IN * T_DIM * V_DIM;
  float* __restrict__ on = out + (size_t)n * C_OUT * T_DIM * V_DIM;

  // zero the padded x_lds tail (tl = 25..31) once for both buffers
  for (int e = tid; e < C_IN * (XROW - TCH); e += 256) {
    const int i = e / (XROW - TCH);
    const int j = e - i * (XROW - TCH);
    x_lds[0][i * XROW + TCH + j] = 0.f;
    x_lds[1][i * XROW + TCH + j] = 0.f;
  }

  // prologue: stage v = 0
  {
    const float4* Wv4 = (const float4*)Weff;
    float4* Wl4 = (float4*)&w_lds[0][0];
    #pragma unroll
    for (int j = 0; j < 8; ++j) Wl4[tid + j * 256] = Wv4[tid + j * 256];
    for (int e = tid; e < C_IN * TCH; e += 256) {
      const int i = e / TCH;
      const int tl = e - i * TCH;
      x_lds[0][i * XROW + tl] = xn[(i * T_DIM + t0 + tl) * V_DIM + 0];
    }
  }
  __syncthreads();

  for (int v = 0; v < V_DIM; ++v) {
    const int cur = v & 1;
    const int nxt = cur ^ 1;

    // issue prefetch of v+1 into registers (latency hidden by compute below)
    float4 wr4[8];
    float  xr[7];
    const bool has_next = (v + 1 < V_DIM);
    if (has_next) {
      const float4* Wv4 = (const float4*)(Weff + (size_t)(v + 1) * C_IN * C_OUT);
      #pragma unroll
      for (int j = 0; j < 8; ++j) wr4[j] = Wv4[tid + j * 256];
      #pragma unroll
      for (int j = 0; j < 7; ++j) {
        const int e = tid + j * 256;
        if (e < C_IN * TCH) {
          const int i = e / TCH;
          const int tl = e - i * TCH;
          xr[j] = xn[(i * T_DIM + t0 + tl) * V_DIM + (v + 1)];
        }
      }
    }

    // compute: 4c x 4t register tile per lane
    float acc[4][4];
    #pragma unroll
    for (int jc = 0; jc < 4; ++jc)
      #pragma unroll
      for (int jt = 0; jt < 4; ++jt) acc[jc][jt] = 0.f;

    #pragma unroll 8
    for (int i = 0; i < C_IN; ++i) {
      const float4 a = *(const float4*)&w_lds[cur][i * C_OUT + c4];
      const float4 b = *(const float4*)&x_lds[cur][i * XROW + t4];
      const float av[4] = {a.x, a.y, a.z, a.w};
      const float bv[4] = {b.x, b.y, b.z, b.w};
      #pragma unroll
      for (int jc = 0; jc < 4; ++jc)
        #pragma unroll
        for (int jt = 0; jt < 4; ++jt)
          acc[jc][jt] = fmaf(av[jc], bv[jt], acc[jc][jt]);
    }

    // epilogue: bias + scattered store (v-stride inherent; L2 merges lines)
    const float4 bb = *(const float4*)&beff[v * C_OUT + c4];
    const float bias4[4] = {bb.x, bb.y, bb.z, bb.w};
    #pragma unroll
    for (int jc = 0; jc < 4; ++jc) {
      float* op = on + ((size_t)(c4 + jc) * T_DIM + t0) * V_DIM + v;
      #pragma unroll
      for (int jt = 0; jt < 4; ++jt) {
        const int tl = t4 + jt;
        if (tl < TCH) op[tl * V_DIM] = acc[jc][jt] + bias4[jc];
      }
    }

    // drain prefetch into the other buffer, then barrier
    if (has_next) {
      float4* Wl4 = (float4*)&w_lds[nxt][0];
      #pragma unroll
      for (int j = 0; j < 8; ++j) Wl4[tid + j * 256] = wr4[j];
      #pragma unroll
      for (int j = 0; j < 7; ++j) {
        const int e = tid + j * 256;
        if (e < C_IN * TCH) {
          const int i = e / TCH;
          const int tl = e - i * TCH;
          x_lds[nxt][i * XROW + tl] = xr[j];
        }
      }
      __syncthreads();
    }
  }
}

extern "C" void kernel_launch(void* const* d_in, const int* in_sizes, int n_in,
                              void* d_out, int out_size, void* d_ws, size_t ws_size,
                              hipStream_t stream) {
  const float* x      = (const float*)d_in[0];
  const float* A      = (const float*)d_in[1];
  const float* weight = (const float*)d_in[2];
  const float* bias   = (const float*)d_in[3];
  const int*   index  = (const int*)d_in[4];
  float* out = (float*)d_out;

  float* Weff = (float*)d_ws;                          // 25*64*128 floats
  float* beff = Weff + (size_t)V_DIM * C_IN * C_OUT;   // 25*128 floats

  sgc_prep<<<dim3(V_DIM), dim3(256), 0, stream>>>(A, weight, bias, index, Weff, beff);
  sgc_main<<<dim3(T_DIM / TCH, N_DIM), dim3(256), 0, stream>>>(x, Weff, beff, out);
}

// Round 2
// 584.996 us; speedup vs baseline: 2.8399x; 2.8399x over previous
//
#include <hip/hip_runtime.h>
#include <cstddef>
#include <cstdint>

#define N_DIM 64
#define C_IN 64
#define C_OUT 128
#define T_DIM 300
#define V_DIM 25
#define TT 8                      // t per block
#define TV (TT * V_DIM)           // 200 contiguous floats per (i) row
#define XROW 8                    // t per i-row in x_lds
#define XPLANE (C_IN * XROW + 4)  // 516: v-plane stride (pad 4 -> bank spread)
#define ORS 210                   // out_lds row stride in bf16 elems (pad 10)

typedef unsigned int uint32;
typedef unsigned short ushort16;

__device__ __forceinline__ ushort16 f2bf(float f) {
  uint32 u = __float_as_uint(f);
  u = (u + 0x7FFFu + ((u >> 16) & 1u)) >> 16;   // RNE
  return (ushort16)u;
}
__device__ __forceinline__ float bf2f(ushort16 h) {
  return __uint_as_float(((uint32)h) << 16);
}

// ---------------- prep: s[k][v] -> Weff bf16 [v][i][c], beff fp32 [v][c] ----
__global__ __launch_bounds__(256)
void sgc_prep(const float* __restrict__ A, const float* __restrict__ W,
              const float* __restrict__ bias, const int* __restrict__ index,
              ushort16* __restrict__ Weff, float* __restrict__ beff) {
  const int v = blockIdx.x;
  const int idx = index[v];
  float s0 = 0.f, s1 = 0.f, s2 = 0.f;
  for (int w = 0; w < V_DIM; ++w) {
    s0 += A[(0 * V_DIM + idx) * V_DIM + w];
    s1 += A[(1 * V_DIM + idx) * V_DIM + w];
    s2 += A[(2 * V_DIM + idx) * V_DIM + w];
  }
  for (int e = threadIdx.x; e < C_IN * C_OUT; e += 256) {
    const int i = e >> 7;
    const int c = e & (C_OUT - 1);
    const float wv = s0 * W[(0 * C_OUT + c) * C_IN + i] +
                     s1 * W[(1 * C_OUT + c) * C_IN + i] +
                     s2 * W[(2 * C_OUT + c) * C_IN + i];
    Weff[v * (C_IN * C_OUT) + i * C_OUT + c] = f2bf(wv);
  }
  if (threadIdx.x < C_OUT) {
    const int c = threadIdx.x;
    beff[v * C_OUT + c] = s0 * bias[0 * C_OUT + c] +
                          s1 * bias[1 * C_OUT + c] +
                          s2 * bias[2 * C_OUT + c];
  }
}

// ---------------- main ------------------------------------------------------
__global__ __launch_bounds__(256, 2)
void sgc_main(const float* __restrict__ x, const ushort16* __restrict__ Weff,
              const float* __restrict__ beff, float* __restrict__ out) {
  __shared__ ushort16 xl[V_DIM * XPLANE];   // 25.8 KB  [v][i][t]
  __shared__ ushort16 ol[C_OUT * ORS];      // 53.76 KB [c][tv(+pad)]

  const int tid = threadIdx.x;
  const int n  = blockIdx.y;
  const int t0 = blockIdx.x * TT;
  const int valid_t  = min(TT, T_DIM - t0);
  const int valid_tv = valid_t * V_DIM;

  const float* __restrict__ xn =
      x + (size_t)n * C_IN * T_DIM * V_DIM + (size_t)t0 * V_DIM;

  // ---- stage x: coalesced float4 over contiguous tv, scatter bf16 to [v][i][t]
  for (int q = tid; q < C_IN * (TV / 4); q += 256) {   // 3200 float4 slots
    const int i  = q / (TV / 4);
    const int r  = q - i * (TV / 4);
    const int j0 = 4 * r;
    const float* src = xn + (size_t)i * (T_DIM * V_DIM) + j0;
    float vals[4];
    if (j0 + 3 < valid_tv) {
      const float4 v4 = *(const float4*)src;
      vals[0] = v4.x; vals[1] = v4.y; vals[2] = v4.z; vals[3] = v4.w;
    } else {
      #pragma unroll
      for (int e = 0; e < 4; ++e) vals[e] = (j0 + e < valid_tv) ? src[e] : 0.f;
    }
    #pragma unroll
    for (int e = 0; e < 4; ++e) {
      const int j = j0 + e;
      const int t = j / V_DIM;
      const int v = j - V_DIM * t;
      xl[v * XPLANE + i * XROW + t] = f2bf(vals[e]);
    }
  }
  __syncthreads();

  // ---- compute: wave w handles v = w, w+4, ... ; lane tile 4c x 4t
  const int wave = tid >> 6;
  const int lane = tid & 63;
  const int cg = lane & 31;
  const int tg = lane >> 5;     // 0..1
  const int c4 = cg * 4;
  const int t4 = tg * 4;

  for (int v = wave; v < V_DIM; v += 4) {
    float acc[4][4];
    #pragma unroll
    for (int a = 0; a < 4; ++a)
      #pragma unroll
      for (int b = 0; b < 4; ++b) acc[a][b] = 0.f;

    const uint2* __restrict__ wrow =
        (const uint2*)(Weff + v * (C_IN * C_OUT) + c4);        // + i*32 (uint2)
    const uint2* __restrict__ xrow =
        (const uint2*)(&xl[v * XPLANE + t4]);                  // + i*2  (uint2)

    #pragma unroll 8
    for (int i = 0; i < C_IN; ++i) {
      const uint2 wb = wrow[i * 32];
      const uint2 xv = xrow[i * 2];
      float wa[4], xb[4];
      wa[0] = __uint_as_float(wb.x << 16);
      wa[1] = __uint_as_float(wb.x & 0xFFFF0000u);
      wa[2] = __uint_as_float(wb.y << 16);
      wa[3] = __uint_as_float(wb.y & 0xFFFF0000u);
      xb[0] = __uint_as_float(xv.x << 16);
      xb[1] = __uint_as_float(xv.x & 0xFFFF0000u);
      xb[2] = __uint_as_float(xv.y << 16);
      xb[3] = __uint_as_float(xv.y & 0xFFFF0000u);
      #pragma unroll
      for (int jc = 0; jc < 4; ++jc)
        #pragma unroll
        for (int jt = 0; jt < 4; ++jt)
          acc[jc][jt] = fmaf(wa[jc], xb[jt], acc[jc][jt]);
    }

    // epilogue: bias (fp32) then bf16 into out-LDS tile [c][t*25+v]
    const float4 bb = *(const float4*)&beff[v * C_OUT + c4];
    const float bias4[4] = {bb.x, bb.y, bb.z, bb.w};
    #pragma unroll
    for (int jc = 0; jc < 4; ++jc)
      #pragma unroll
      for (int jt = 0; jt < 4; ++jt)
        ol[(c4 + jc) * ORS + (t4 + jt) * V_DIM + v] = f2bf(acc[jc][jt] + bias4[jc]);
  }
  __syncthreads();

  // ---- flush: contiguous float4 stores over (t,v)-flat rows
  {
    const int c = tid >> 1;
    const int h = tid & 1;
    const int jbase = h * (TV / 2);
    float* __restrict__ orow =
        out + (size_t)n * C_OUT * T_DIM * V_DIM +
        (size_t)c * (T_DIM * V_DIM) + (size_t)t0 * V_DIM;
    const ushort16* __restrict__ lrow = &ol[c * ORS];
    for (int jj = 0; jj < TV / 2; jj += 4) {
      const int j = jbase + jj;
      if (j + 3 < valid_tv) {
        float4 o4;
        o4.x = bf2f(lrow[j + 0]);
        o4.y = bf2f(lrow[j + 1]);
        o4.z = bf2f(lrow[j + 2]);
        o4.w = bf2f(lrow[j + 3]);
        *(float4*)(orow + j) = o4;
      } else {
        #pragma unroll
        for (int e = 0; e < 4; ++e)
          if (j + e < valid_tv) orow[j + e] = bf2f(lrow[j + e]);
      }
    }
  }
}

extern "C" void kernel_launch(void* const* d_in, const int* in_sizes, int n_in,
                              void* d_out, int out_size, void* d_ws, size_t ws_size,
                              hipStream_t stream) {
  const float* x      = (const float*)d_in[0];
  const float* A      = (const float*)d_in[1];
  const float* weight = (const float*)d_in[2];
  const float* bias   = (const float*)d_in[3];
  const int*   index  = (const int*)d_in[4];
  float* out = (float*)d_out;

  ushort16* Weff = (ushort16*)d_ws;                       // 25*64*128 bf16 = 409.6 KB
  float* beff = (float*)((char*)d_ws + 409600);           // 25*128 fp32

  sgc_prep<<<dim3(V_DIM), dim3(256), 0, stream>>>(A, weight, bias, index, Weff, beff);
  sgc_main<<<dim3((T_DIM + TT - 1) / TT, N_DIM), dim3(256), 0, stream>>>(x, Weff, beff, out);
}